// Round 9
// baseline (113.406 us; speedup 1.0000x reference)
//
#include <hip/hip_runtime.h>

#define NK3 30  // 3*K columns per node
#define NKP 15  // float2 pairs per row

__device__ __forceinline__ float hw_log2(float a) { return __builtin_amdgcn_logf(a); }
__device__ __forceinline__ float hw_exp2(float a) { return __builtin_amdgcn_exp2f(a); }
__device__ __forceinline__ float hw_rcp(float a)  { return __builtin_amdgcn_rcpf(a); }

// Math: e_nj = exp(x_n + gumbel_nj) = exp2(x_n*log2e) * rcp(-log2 u_nj) * (1/ln2)
//       [the 1/ln2 cancels in the probs ratio]
// denom'_j = sum_n exp2(xe_n)*rcp(w_nj);  out = exp2(xe)*max_j(r_j * rcp(denom'_j)).

// ---------------- K0: zero the workspace ----------------
__global__ __launch_bounds__(256) void k0_zero(float4* __restrict__ ws, int count4)
{
    const int i = blockIdx.x * 256 + threadIdx.x;
    if (i < count4) ws[i] = make_float4(0.f, 0.f, 0.f, 0.f);
}

// ---------------- K1: row-per-lane + masked wave butterfly ----------------
// 64 nodes per wave, node = base+lane. Each lane loads ITS row (15 float2, 30
// values all simultaneously live -> compiler cannot sink the loads; same shape
// as the proven-fast k3). Per distinct segment in the window (wave-uniform
// short loop, ~1.25 avg), masked 64-lane xor-butterfly per column, then 30
// predicated atomicAdds. Branch-free inner math.
__global__ __launch_bounds__(256) void k1_accumulate(
    const float* __restrict__ x, const float* __restrict__ uniforms,
    const int* __restrict__ ptr, float* __restrict__ wsum, int N, int B)
{
    const int wid  = (blockIdx.x << 2) + (threadIdx.x >> 6);
    const int lane = threadIdx.x & 63;
    const int base = wid << 6;  // 64 nodes / wave
    if (base >= N) return;

    const int n  = base + lane;
    const int nv = (n < N) ? n : (N - 1);   // clamped (N is 64-multiple; defensive)
    const bool valid = (n < N);

    // per-lane segment via binary search (ptr is L1/L2-hot)
    int lo = 0, hi = B;
    while (hi - lo > 1) { int mid = (lo + hi) >> 1; if (ptr[mid] <= nv) lo = mid; else hi = mid; }
    const int seg = lo;

    // load row + compute r_j = exp2(xe) * rcp(-log2 u_j); all 30 live at once
    const float2* row = reinterpret_cast<const float2*>(uniforms + (size_t)nv * NK3);
    float2 u[NKP];
#pragma unroll
    for (int k = 0; k < NKP; ++k) u[k] = row[k];
    const float E = hw_exp2(x[nv] * 1.44269504f);

    float r[NK3];
#pragma unroll
    for (int k = 0; k < NKP; ++k) {
        r[2 * k]     = E * hw_rcp(-hw_log2(u[k].x));
        r[2 * k + 1] = E * hw_rcp(-hw_log2(u[k].y));
    }

    // distinct segments in this window (seg is monotone in lane)
    const int s_lo = __shfl(seg, 0, 64);
    const int s_hi = __shfl(seg, 63, 64);

    for (int s = s_lo; s <= s_hi; ++s) {   // wave-uniform loop, usually 1 iter
        const bool mine = valid && (seg == s);
        float v[NK3];
#pragma unroll
        for (int j = 0; j < NK3; ++j) v[j] = mine ? r[j] : 0.0f;
#pragma unroll
        for (int j = 0; j < NK3; ++j) {
#pragma unroll
            for (int off = 1; off < 64; off <<= 1)
                v[j] += __shfl_xor(v[j], off, 64);
        }
#pragma unroll
        for (int j = 0; j < NK3; ++j)
            if (lane == j) atomicAdd(&wsum[(size_t)s * NK3 + j], v[j]);
    }
}

// ---------------- K3: out[n] = exp2(xe) * max_j (r_j * rcp(den_j)) ----------------
// 256 nodes per wave (4 chunks of 64), row-per-lane; rcp applied inline to the
// 30 loaded denominators (no separate k2 pass).
__global__ __launch_bounds__(256) void k3_output(
    const float* __restrict__ x, const float* __restrict__ uniforms,
    const int* __restrict__ ptr, const float* __restrict__ den,
    float* __restrict__ out, int N, int B)
{
    const int wid  = (blockIdx.x << 2) + (threadIdx.x >> 6);
    const int lane = threadIdx.x & 63;
    const int base = wid << 8;  // 256 nodes / wave
    if (base >= N) return;

    const int n0 = base + lane;
    int lo = 0, hi = B;
    while (hi - lo > 1) { int mid = (lo + hi) >> 1; if (ptr[mid] <= n0) lo = mid; else hi = mid; }
    int seg = lo;

    for (int c = 0; c < 4; ++c) {
        const int n = base + (c << 6) + lane;
        if (n >= N) return;
        while (n >= ptr[seg + 1]) ++seg;  // monotone advance, L1-hot

        float l[NK3];
#pragma unroll
        for (int j = 0; j < NK3; ++j) l[j] = hw_rcp(den[seg * NK3 + j]);

        const float2* row = reinterpret_cast<const float2*>(uniforms + (size_t)n * NK3);
        float mx = 0.0f;
#pragma unroll
        for (int k = 0; k < NKP; ++k) {
            const float2 u = row[k];
            const float r0 = hw_rcp(-hw_log2(u.x));
            const float r1 = hw_rcp(-hw_log2(u.y));
            mx = fmaxf(mx, fmaxf(r0 * l[2 * k], r1 * l[2 * k + 1]));
        }
        out[n] = hw_exp2(x[n] * 1.44269504f) * mx;
    }
}

// ---------------- Fallback: single kernel (if ws too small) ----------------
__global__ __launch_bounds__(256) void gnn_fallback(
    const float* __restrict__ x, const float* __restrict__ uniforms,
    const int* __restrict__ ptr, float* __restrict__ out)
{
    const int wave = threadIdx.x >> 6;
    const int lane = threadIdx.x & 63;
    const int g = (blockIdx.x << 2) + wave;
    const int start = ptr[g];
    const int end   = ptr[g + 1];
    if (end <= start) return;

    float acc[NK3];
#pragma unroll
    for (int j = 0; j < NK3; ++j) acc[j] = 0.0f;
    const int iters = (end - start + 63) >> 6;

    for (int it = 0; it < iters; ++it) {
        const int n = start + (it << 6) + lane;
        if (n < end) {
            const float E = hw_exp2(x[n] * 1.44269504f);
            const float2* row = reinterpret_cast<const float2*>(uniforms + (size_t)n * NK3);
#pragma unroll
            for (int k = 0; k < NKP; ++k) {
                float2 u = row[k];
                acc[2 * k]     = fmaf(E, hw_rcp(-hw_log2(u.x)), acc[2 * k]);
                acc[2 * k + 1] = fmaf(E, hw_rcp(-hw_log2(u.y)), acc[2 * k + 1]);
            }
        }
    }
#pragma unroll
    for (int j = 0; j < NK3; ++j) {
        float v = acc[j];
#pragma unroll
        for (int off = 1; off < 64; off <<= 1) v += __shfl_xor(v, off, 64);
        acc[j] = hw_rcp(v);
    }
    for (int it = 0; it < iters; ++it) {
        const int n = start + (it << 6) + lane;
        if (n < end) {
            const float2* row = reinterpret_cast<const float2*>(uniforms + (size_t)n * NK3);
            float mx = 0.0f;
#pragma unroll
            for (int k = 0; k < NKP; ++k) {
                float2 u = row[k];
                const float r0 = hw_rcp(-hw_log2(u.x));
                const float r1 = hw_rcp(-hw_log2(u.y));
                mx = fmaxf(mx, fmaxf(r0 * acc[2 * k], r1 * acc[2 * k + 1]));
            }
            out[n] = hw_exp2(x[n] * 1.44269504f) * mx;
        }
    }
}

extern "C" void kernel_launch(void* const* d_in, const int* in_sizes, int n_in,
                              void* d_out, int out_size, void* d_ws, size_t ws_size,
                              hipStream_t stream) {
    const float* x        = (const float*)d_in[0];
    const float* uniforms = (const float*)d_in[1];
    const int*   ptr      = (const int*)d_in[2];
    float* out = (float*)d_out;

    const int N = in_sizes[0];
    const int B = in_sizes[2] - 1;
    const size_t ws_needed = (size_t)B * NK3 * sizeof(float);

    if (ws_size >= ws_needed && d_ws != nullptr) {
        float* wsum = (float*)d_ws;

        const int cnt  = B * NK3;            // 122880 floats
        const int cnt4 = cnt >> 2;
        const int b0 = (cnt4 + 255) / 256;
        k0_zero<<<b0, 256, 0, stream>>>((float4*)wsum, cnt4);

        const int waves1 = (N + 63) / 64;    // 64 nodes / wave
        const int b1 = (waves1 + 3) / 4;
        k1_accumulate<<<b1, 256, 0, stream>>>(x, uniforms, ptr, wsum, N, B);

        const int b3 = (N + 1023) / 1024;    // 4 waves x 256 nodes
        k3_output<<<b3, 256, 0, stream>>>(x, uniforms, ptr, wsum, out, N, B);
    } else {
        const int blocks = (B + 3) / 4;
        gnn_fallback<<<blocks, 256, 0, stream>>>(x, uniforms, ptr, out);
    }
}